// Round 2
// baseline (72.753 us; speedup 1.0000x reference)
//
#include <hip/hip_runtime.h>
#include <math.h>

// Chamfer loss: B=4, N=M=8192, 3-D fp32 points.
// loss = (1/(B*N)) sum_i max(min_j d2, 0) + (1/(B*M)) sum_j max(min_i d2, 0)
//        + lam * mean(fbpp)
// Inner: min_j(|y|^2 - 2 x.y) + |x|^2, with (-2y, |y|^2) precomputed so the
// per-pair cost is 3 fma + 0.5 v_min3  (~3.6 VALU ops/pair).

#define SPLITS 16     // waves per block; each owns a contiguous y-chunk
#define IX     4      // x-points per thread
#define PTS    256    // x-points per block = 64 lanes * IX

__device__ __forceinline__ float min3f(float a, float b, float c) {
    float d;
    asm("v_min3_f32 %0, %1, %2, %3" : "=v"(d) : "v"(a), "v"(b), "v"(c));
    return d;
}

// yt[0 .. B*N)          = transformed pred
// yt[B*N .. B*N + B*M)  = transformed targ
__global__ __launch_bounds__(256) void transform_kernel(
    const float* __restrict__ pred, const float* __restrict__ targ,
    int B, int N, int M, float4* __restrict__ yt)
{
    const int idx = blockIdx.x * 256 + threadIdx.x;
    const int totP = B * N, totT = B * M;
    if (idx < totP) {
        const float* p = pred + (size_t)idx * 3;
        const float x = p[0], y = p[1], z = p[2];
        yt[idx] = make_float4(-2.f*x, -2.f*y, -2.f*z, x*x + y*y + z*z);
    }
    if (idx < totT) {
        const float* p = targ + (size_t)idx * 3;
        const float x = p[0], y = p[1], z = p[2];
        yt[totP + idx] = make_float4(-2.f*x, -2.f*y, -2.f*z, x*x + y*y + z*z);
    }
}

__global__ __launch_bounds__(1024) void chamfer_main(
    const float* __restrict__ pred, const float* __restrict__ targ,
    const float4* __restrict__ yt, int B, int N, int M,
    float* __restrict__ partial)
{
    const int dir = blockIdx.z;          // 0: pred->targ, 1: targ->pred
    const int b   = blockIdx.y;

    const float* __restrict__ xs = (dir == 0) ? pred : targ;
    const int Nx = (dir == 0) ? N : M;
    const int My = (dir == 0) ? M : N;
    // y side uses the OPPOSITE (transformed) array
    const size_t ybase = (dir == 0) ? ((size_t)B * N + (size_t)b * M)
                                    : ((size_t)b * N);

    const int tid  = threadIdx.x;
    const int w    = tid >> 6;           // wave index = y-split
    const int lane = tid & 63;

    __shared__ float red[SPLITS][PTS];   // 16 KB

    // ---- this thread's IX x-points ----
    const int p0 = blockIdx.x * PTS + lane * IX;
    float px[IX], py[IX], pz[IX], n2x[IX];
    bool  valid[IX];
    #pragma unroll
    for (int k = 0; k < IX; ++k) {
        const int p = p0 + k;
        valid[k] = (p < Nx);
        if (valid[k]) {
            const float* xp = xs + ((size_t)b * Nx + p) * 3;
            px[k] = xp[0]; py[k] = xp[1]; pz[k] = xp[2];
            n2x[k] = px[k]*px[k] + py[k]*py[k] + pz[k]*pz[k];
        } else {
            px[k] = py[k] = pz[k] = n2x[k] = 0.0f;
        }
    }

    float best[IX];
    #pragma unroll
    for (int k = 0; k < IX; ++k) best[k] = INFINITY;

    // ---- this wave's contiguous y-chunk (uniform addresses, L2-resident) --
    const int chunk = (My + SPLITS - 1) / SPLITS;
    const int y0 = __builtin_amdgcn_readfirstlane(w * chunk);
    const int y1 = min(My, y0 + chunk);
    const float4* __restrict__ yc = yt + ybase;

    int j = y0;
    for (; j + 8 <= y1; j += 8) {
        #pragma unroll
        for (int u = 0; u < 8; u += 2) {
            const float4 qa = yc[j + u];
            const float4 qb = yc[j + u + 1];
            #pragma unroll
            for (int k = 0; k < IX; ++k) {
                const float va = fmaf(qa.x, px[k],
                                 fmaf(qa.y, py[k],
                                 fmaf(qa.z, pz[k], qa.w)));
                const float vb = fmaf(qb.x, px[k],
                                 fmaf(qb.y, py[k],
                                 fmaf(qb.z, pz[k], qb.w)));
                best[k] = min3f(va, vb, best[k]);
            }
        }
    }
    for (; j < y1; ++j) {
        const float4 q = yc[j];
        #pragma unroll
        for (int k = 0; k < IX; ++k) {
            const float v = fmaf(q.x, px[k],
                            fmaf(q.y, py[k],
                            fmaf(q.z, pz[k], q.w)));
            best[k] = fminf(best[k], v);
        }
    }

    // ---- per-point value (add |x|^2, clamp >= 0); invalid -> 0 ----
    #pragma unroll
    for (int k = 0; k < IX; ++k) {
        const float v = valid[k] ? fmaxf(best[k] + n2x[k], 0.0f) : 0.0f;
        red[w][lane * IX + k] = v;
    }
    __syncthreads();

    // min across the 16 splits for each of the 256 points
    if (tid < PTS) {
        float m = red[0][tid];
        #pragma unroll
        for (int s2 = 1; s2 < SPLITS; ++s2) m = fminf(m, red[s2][tid]);
        red[0][tid] = m;
    }
    __syncthreads();

    // sum the 256 per-point mins (deterministic tree)
    for (int off = PTS / 2; off > 0; off >>= 1) {
        if (tid < off) red[0][tid] += red[0][tid + off];
        __syncthreads();
    }

    if (tid == 0) {
        const size_t flat = ((size_t)dir * gridDim.y + b) * gridDim.x
                            + blockIdx.x;
        partial[flat] = red[0][0];
    }
}

__global__ void finalize_kernel(const float* __restrict__ partial,
                                int ntot, int half,
                                float invBN, float invBM,
                                const float* __restrict__ fbpp, int Bf,
                                const void* __restrict__ lamp,
                                float* __restrict__ out)
{
    __shared__ float sb[256];
    const int tid = threadIdx.x;
    float acc = 0.0f;
    for (int i = tid; i < ntot; i += 256)
        acc += partial[i] * (i < half ? invBN : invBM);
    sb[tid] = acc;
    __syncthreads();
    for (int off = 128; off > 0; off >>= 1) {
        if (tid < off) sb[tid] += sb[tid + off];
        __syncthreads();
    }
    if (tid == 0) {
        const int li = *(const int*)lamp;
        const float lam = (li >= -1000000 && li <= 1000000)
                            ? (float)li : *(const float*)lamp;
        float fm = 0.0f;
        for (int i = 0; i < Bf; ++i) fm += fbpp[i];
        fm /= (float)Bf;
        out[0] = sb[0] + lam * fm;
    }
}

extern "C" void kernel_launch(void* const* d_in, const int* in_sizes, int n_in,
                              void* d_out, int out_size, void* d_ws, size_t ws_size,
                              hipStream_t stream) {
    const float* pred = (const float*)d_in[0];
    const float* targ = (const float*)d_in[1];
    const float* fbpp = (const float*)d_in[2];
    const void*  lamp = d_in[3];

    const int B = in_sizes[2];
    const int N = in_sizes[0] / (3 * B);
    const int M = in_sizes[1] / (3 * B);

    float4* yt      = (float4*)d_ws;
    const size_t ytElems = (size_t)B * N + (size_t)B * M;
    float*  partial = (float*)((char*)d_ws + ytElems * sizeof(float4));

    // ---- pre-transform: (-2y, |y|^2) for both clouds ----
    const int totmax = B * ((N > M) ? N : M);
    transform_kernel<<<(totmax + 255) / 256, 256, 0, stream>>>(
        pred, targ, B, N, M, yt);

    // ---- main pair sweep ----
    const int nmax = (N > M) ? N : M;
    const int gx = (nmax + PTS - 1) / PTS;
    dim3 grid(gx, B, 2), block(1024);
    chamfer_main<<<grid, block, 0, stream>>>(pred, targ, yt, B, N, M, partial);

    // ---- finalize ----
    const int half = gx * B;
    const int ntot = 2 * half;
    finalize_kernel<<<1, 256, 0, stream>>>(partial, ntot, half,
                                           1.0f / ((float)B * (float)N),
                                           1.0f / ((float)B * (float)M),
                                           fbpp, B, lamp, (float*)d_out);
}

// Round 3
// 55.397 us; speedup vs baseline: 1.3133x; 1.3133x over previous
//
#include <hip/hip_runtime.h>
#include <math.h>

// Chamfer loss: B=4, N=M=8192, 3-D fp32 points.
// loss = (1/(B*N)) sum_i max(min_j d2,0) + (1/(B*M)) sum_j max(min_i d2,0)
//        + lam*mean(fbpp)
// Inner value: min_j(|y|^2 - 2 x.y) + |x|^2 with (-2y,|y|^2) precomputed.
// Per-pair cost: 3 fma + 0.5 v_min3 = 3.5 VALU ops.

#define SPLITS 16     // waves per block (y-split within block)
#define IX     8      // x-points per thread
#define PTS    512    // x-points per block = 64 lanes * IX
#define TILE   2048   // y-points staged per LDS tile (32 KB)

__device__ __forceinline__ float min3f(float a, float b, float c) {
    float d;
    asm("v_min3_f32 %0, %1, %2, %3" : "=v"(d) : "v"(a), "v"(b), "v"(c));
    return d;
}

// yt[0 .. B*N)         = transformed pred: (-2p, |p|^2)
// yt[B*N .. B*N+B*M)   = transformed targ
__global__ __launch_bounds__(256) void transform_kernel(
    const float* __restrict__ pred, const float* __restrict__ targ,
    int B, int N, int M, float4* __restrict__ yt)
{
    const int idx = blockIdx.x * 256 + threadIdx.x;
    const int totP = B * N, totT = B * M;
    if (idx < totP) {
        const float* p = pred + (size_t)idx * 3;
        const float x = p[0], y = p[1], z = p[2];
        yt[idx] = make_float4(-2.f*x, -2.f*y, -2.f*z, x*x + y*y + z*z);
    }
    if (idx < totT) {
        const float* p = targ + (size_t)idx * 3;
        const float x = p[0], y = p[1], z = p[2];
        yt[totP + idx] = make_float4(-2.f*x, -2.f*y, -2.f*z, x*x + y*y + z*z);
    }
}

// grid: (Nmax/PTS, B, 2*YS).  z = dir*YS + ys.
// Writes per-x-point raw minima (min_j of |y|^2-2x.y over this block's
// y-range) to best2[((ys*2+dir)*B + b)*Nmax + x].
__global__ __launch_bounds__(1024) void chamfer_main(
    const float* __restrict__ pred, const float* __restrict__ targ,
    const float4* __restrict__ yt, int B, int N, int M, int YS, int Nmax,
    float* __restrict__ best2)
{
    const int zz  = blockIdx.z;
    const int dir = zz / YS;
    const int ys  = zz - dir * YS;
    const int b   = blockIdx.y;

    const float* __restrict__ xs = (dir == 0) ? pred : targ;
    const int Nx = (dir == 0) ? N : M;
    const int My = (dir == 0) ? M : N;
    const size_t ybase = (dir == 0) ? ((size_t)B * N + (size_t)b * M)
                                    : ((size_t)b * N);

    const int tid  = threadIdx.x;
    const int w    = tid >> 6;
    const int lane = tid & 63;

    __shared__ float4 ytile[TILE];       // 32 KB
    __shared__ float  red[SPLITS][PTS];  // 32 KB

    // ---- load 8 x-points/thread via 6 aligned float4 loads ----
    const int p0 = blockIdx.x * PTS + lane * IX;
    float px[IX], py[IX], pz[IX];
    if (p0 + IX <= Nx) {
        const float4* xp = (const float4*)(xs + ((size_t)b * Nx + p0) * 3);
        const float4 r0 = xp[0], r1 = xp[1], r2 = xp[2];
        const float4 r3 = xp[3], r4 = xp[4], r5 = xp[5];
        px[0]=r0.x; py[0]=r0.y; pz[0]=r0.z;
        px[1]=r0.w; py[1]=r1.x; pz[1]=r1.y;
        px[2]=r1.z; py[2]=r1.w; pz[2]=r2.x;
        px[3]=r2.y; py[3]=r2.z; pz[3]=r2.w;
        px[4]=r3.x; py[4]=r3.y; pz[4]=r3.z;
        px[5]=r3.w; py[5]=r4.x; pz[5]=r4.y;
        px[6]=r4.z; py[6]=r4.w; pz[6]=r5.x;
        px[7]=r5.y; py[7]=r5.z; pz[7]=r5.w;
    } else {
        #pragma unroll
        for (int k = 0; k < IX; ++k) {
            const int p = p0 + k;
            if (p < Nx) {
                const float* xp = xs + ((size_t)b * Nx + p) * 3;
                px[k]=xp[0]; py[k]=xp[1]; pz[k]=xp[2];
            } else { px[k]=py[k]=pz[k]=0.f; }
        }
    }

    float best[IX];
    #pragma unroll
    for (int k = 0; k < IX; ++k) best[k] = INFINITY;

    // ---- this block's y-range, tiled through LDS ----
    const int chunk = (My + YS - 1) / YS;
    const int yb0 = ys * chunk;
    const int yb1 = min(My, yb0 + chunk);

    for (int t0 = yb0; t0 < yb1; t0 += TILE) {
        const int cnt = min(TILE, yb1 - t0);
        __syncthreads();
        for (int idx = tid; idx < cnt; idx += 1024)
            ytile[idx] = yt[ybase + t0 + idx];
        __syncthreads();

        // wave w consumes a contiguous sub-chunk; lane-uniform addresses
        // -> ds_read_b128 broadcast, zero bank conflicts
        const int cw = (cnt + SPLITS - 1) / SPLITS;
        const int j0 = w * cw;
        const int j1 = min(cnt, j0 + cw);
        int j = j0;
        for (; j + 4 <= j1; j += 4) {
            const float4 qa = ytile[j],     qb = ytile[j + 1];
            const float4 qc = ytile[j + 2], qd = ytile[j + 3];
            #pragma unroll
            for (int k = 0; k < IX; ++k) {
                const float va = fmaf(qa.x, px[k], fmaf(qa.y, py[k],
                                 fmaf(qa.z, pz[k], qa.w)));
                const float vb = fmaf(qb.x, px[k], fmaf(qb.y, py[k],
                                 fmaf(qb.z, pz[k], qb.w)));
                const float vc = fmaf(qc.x, px[k], fmaf(qc.y, py[k],
                                 fmaf(qc.z, pz[k], qc.w)));
                const float vd = fmaf(qd.x, px[k], fmaf(qd.y, py[k],
                                 fmaf(qd.z, pz[k], qd.w)));
                best[k] = min3f(va, vb, best[k]);
                best[k] = min3f(vc, vd, best[k]);
            }
        }
        for (; j < j1; ++j) {
            const float4 q = ytile[j];
            #pragma unroll
            for (int k = 0; k < IX; ++k) {
                const float v = fmaf(q.x, px[k], fmaf(q.y, py[k],
                                fmaf(q.z, pz[k], q.w)));
                best[k] = fminf(best[k], v);
            }
        }
    }

    // ---- cross-wave min, then store per-point raw minima ----
    #pragma unroll
    for (int k = 0; k < IX; ++k)
        red[w][lane * IX + k] = best[k];
    __syncthreads();

    if (tid < PTS) {
        float m = red[0][tid];
        #pragma unroll
        for (int s2 = 1; s2 < SPLITS; ++s2) m = fminf(m, red[s2][tid]);
        best2[((size_t)(ys * 2 + dir) * B + b) * Nmax
              + (size_t)blockIdx.x * PTS + tid] = m;
    }
}

// min across YS splits, add |x|^2 (from yt.w), clamp, weighted block sum.
__global__ __launch_bounds__(256) void combine_kernel(
    const float* __restrict__ best2, const float4* __restrict__ yt,
    int B, int N, int M, int YS, int Nmax,
    float invBN, float invBM, float* __restrict__ partial)
{
    const int tid = threadIdx.x;
    const int tot = 2 * B * Nmax;
    const int gs  = gridDim.x * 256;
    float acc = 0.f;
    for (int idx = blockIdx.x * 256 + tid; idx < tot; idx += gs) {
        const int i   = idx % Nmax;
        const int rem = idx / Nmax;
        const int b   = rem % B;
        const int dir = rem / B;
        const int Nx  = (dir == 0) ? N : M;
        if (i < Nx) {
            float m = best2[((size_t)dir * B + b) * Nmax + i];
            for (int s = 1; s < YS; ++s)
                m = fminf(m, best2[((size_t)(s * 2 + dir) * B + b) * Nmax + i]);
            const size_t xb = (dir == 0) ? ((size_t)b * N)
                                         : ((size_t)B * N + (size_t)b * M);
            const float n2 = ((const float*)&yt[xb + i])[3];
            acc += fmaxf(m + n2, 0.f) * ((dir == 0) ? invBN : invBM);
        }
    }
    __shared__ float sb[256];
    sb[tid] = acc;
    __syncthreads();
    for (int off = 128; off > 0; off >>= 1) {
        if (tid < off) sb[tid] += sb[tid + off];
        __syncthreads();
    }
    if (tid == 0) partial[blockIdx.x] = sb[0];
}

__global__ void finalize_kernel(const float* __restrict__ partial, int np,
                                const float* __restrict__ fbpp, int Bf,
                                const void* __restrict__ lamp,
                                float* __restrict__ out)
{
    __shared__ float sb[256];
    const int tid = threadIdx.x;
    float acc = 0.f;
    for (int i = tid; i < np; i += 256) acc += partial[i];
    sb[tid] = acc;
    __syncthreads();
    for (int off = 128; off > 0; off >>= 1) {
        if (tid < off) sb[tid] += sb[tid + off];
        __syncthreads();
    }
    if (tid == 0) {
        const int li = *(const int*)lamp;
        const float lam = (li >= -1000000 && li <= 1000000)
                            ? (float)li : *(const float*)lamp;
        float fm = 0.f;
        for (int i = 0; i < Bf; ++i) fm += fbpp[i];
        fm /= (float)Bf;
        out[0] = sb[0] + lam * fm;
    }
}

extern "C" void kernel_launch(void* const* d_in, const int* in_sizes, int n_in,
                              void* d_out, int out_size, void* d_ws, size_t ws_size,
                              hipStream_t stream) {
    const float* pred = (const float*)d_in[0];
    const float* targ = (const float*)d_in[1];
    const float* fbpp = (const float*)d_in[2];
    const void*  lamp = d_in[3];

    const int B = in_sizes[2];
    const int N = in_sizes[0] / (3 * B);
    const int M = in_sizes[1] / (3 * B);
    const int Nmax = (N > M) ? N : M;

    // ---- workspace layout ----
    const size_t ytElems = (size_t)B * (N + M);
    float4* yt = (float4*)d_ws;
    size_t off = ytElems * sizeof(float4);

    // y-split factor: 2 if workspace fits the per-split minima, else 1
    const int gxm = (Nmax + PTS - 1) / PTS;
    const int gc  = 256;  // combine blocks
    int YS = 2;
    {
        const size_t need2 = off + (size_t)2 * 2 * B * Nmax * 4 + gc * 4;
        if (need2 > ws_size) YS = 1;
    }
    float* best2 = (float*)((char*)d_ws + off);
    off += (size_t)YS * 2 * B * Nmax * sizeof(float);
    float* partial = (float*)((char*)d_ws + off);

    // ---- 1) pre-transform both clouds to (-2y, |y|^2) ----
    const int totmax = B * Nmax;
    transform_kernel<<<(totmax + 255) / 256, 256, 0, stream>>>(
        pred, targ, B, N, M, yt);

    // ---- 2) main pair sweep ----
    dim3 grid(gxm, B, 2 * YS), block(1024);
    chamfer_main<<<grid, block, 0, stream>>>(pred, targ, yt, B, N, M,
                                             YS, Nmax, best2);

    // ---- 3) combine splits + clamp + weighted sum ----
    combine_kernel<<<gc, 256, 0, stream>>>(best2, yt, B, N, M, YS, Nmax,
                                           1.f / ((float)B * (float)N),
                                           1.f / ((float)B * (float)M),
                                           partial);

    // ---- 4) finalize ----
    finalize_kernel<<<1, 256, 0, stream>>>(partial, gc, fbpp, B, lamp,
                                           (float*)d_out);
}